// Round 1
// baseline (1840.668 us; speedup 1.0000x reference)
//
#include <hip/hip_runtime.h>
#include <stdint.h>

// Problem shape (fixed by reference): M = B*S = 8192, K = 4096, N = 16384
#define M_TOT 8192
#define K_TOT 4096
#define N_TOT 16384

#define BM 256
#define BN 256
#define BK 64
#define NT (K_TOT / BK)   // 64 K-tiles

typedef __attribute__((ext_vector_type(8))) short shortx8;   // 8 bf16 (4 VGPRs)
typedef __attribute__((ext_vector_type(4))) float floatx4;   // MFMA C/D

struct alignas(8) us4 { unsigned short x, y, z, w; };

// float -> bf16 RNE (exact for small ints)
__device__ inline unsigned short f2bf(float f) {
    unsigned int u = __float_as_uint(f);
    return (unsigned short)((u + 0x7fffu + ((u >> 16) & 1u)) >> 16);
}

// ---------------- conversion pre-passes (memory-bound, unchanged) ----------------

__global__ __launch_bounds__(256) void cvt_a_kernel(const float* __restrict__ in,
                                                    unsigned short* __restrict__ out) {
    size_t i = ((size_t)blockIdx.x * 256 + threadIdx.x) * 4;
    float4 v = *(const float4*)(in + i);
    us4 o;
    o.x = f2bf(v.x); o.y = f2bf(v.y); o.z = f2bf(v.z); o.w = f2bf(v.w);
    *(us4*)(out + i) = o;
}

__global__ __launch_bounds__(256) void cvt_w_kernel(const int* __restrict__ in,
                                                    unsigned short* __restrict__ out) {
    size_t i = ((size_t)blockIdx.x * 256 + threadIdx.x) * 4;
    int4 v = *(const int4*)(in + i);
    us4 o;  // int8-valued -> exact in bf16
    o.x = f2bf((float)v.x); o.y = f2bf((float)v.y);
    o.z = f2bf((float)v.z); o.w = f2bf((float)v.w);
    *(us4*)(out + i) = o;
}

// ---------------- 256x256 8-phase bf16 MFMA GEMM (m201-style template) ----------------
//
// LDS: per matrix [2 buf][2 kslice][256 rows][32 cols] bf16, each (buf,ks) region
// 16 KB contiguous. XOR swizzle within a row: colByte ^= ((row>>1)&3)<<4 — spreads
// 16 consecutive rows over all 8 16B bank-groups (2-way residual = free).
// global_load_lds writes linearly; the *global source* address carries the inverse
// (= same) swizzle (rule #21: both-sides-or-neither).
//
// Phase schedule per K-tile t (cur = t&1, nxt = cur^1), 8 waves lockstep:
//   P0 (ks0,nhLo): read A-k0 frags(8) + W-k0 lo(2) | stage W-k1(t+1) -> (nxt,1) | MFMA 16
//   P1 (ks0,nhHi): read W-k0 hi(2)                 | stage A-k0(t+2) -> (cur,0) | MFMA 16
//   P2 (ks1,nhLo): read A-k1 frags(8) + W-k1 lo(2) | stage W-k0(t+2) -> (cur,0W)| MFMA 16
//   P3 (ks1,nhHi): read W-k1 hi(2)                 | stage A-k1(t+2) -> (cur,1) | MFMA 16
//                  vmcnt(6) (3 half-tiles in flight), barrier.
// Each stage overwrites a region whose last reader finished a phase earlier (barrier
// between). vmcnt(6) at tile end guarantees all 4 halves of tile t+1 have landed.

__device__ __forceinline__ void gload_lds16(const void* g, void* l) {
    __builtin_amdgcn_global_load_lds((const __attribute__((address_space(1))) void*)g,
                                     (__attribute__((address_space(3))) void*)l,
                                     16, 0, 0);
}

#define BAR()     asm volatile("s_barrier" ::: "memory")
#define VMCNT(n)  asm volatile("s_waitcnt vmcnt(" #n ")" ::: "memory")

#define REG4(base, buf, ks) ((base) + ((((buf) << 1) | (ks)) * 16384))

__global__ __launch_bounds__(512, 2) void gemm_bf16_kernel(
        const unsigned short* __restrict__ A,   // [M][K] bf16 bits
        const unsigned short* __restrict__ W,   // [N][K] bf16 bits (B^T layout)
        const float* __restrict__ scale,        // [N]
        const float* __restrict__ bias,         // [N]
        float* __restrict__ out)                // [M][N]
{
    __shared__ unsigned short sA[2][2][256][32];   // 64 KB
    __shared__ unsigned short sW[2][2][256][32];   // 64 KB

    const int tid  = threadIdx.x;
    const int lane = tid & 63;
    const int wave = tid >> 6;
    const int l15  = lane & 15;
    const int quad = lane >> 4;

    // XCD-aware bijective swizzle (nwg = 2048, divisible by 8)
    const int NXB = N_TOT / BN;                 // 64
    const int NWG = (M_TOT / BM) * NXB;         // 2048
    int wg  = blockIdx.x;
    int swz = (wg & 7) * (NWG >> 3) + (wg >> 3);
    const int nBlk = (swz & (NXB - 1)) * BN;
    const int mBlk = (swz / NXB) * BM;

    const int waveM = (wave >> 2) * 128;        // 2 M-groups of 128 rows
    const int waveN = (wave & 3) * 64;          // 4 N-groups of 64 cols

    // Per-lane swizzled byte offsets within a 16 KB (256x32 bf16) region
    int offA[8], offW[4];
#pragma unroll
    for (int m = 0; m < 8; ++m) {
        int row = waveM + m * 16 + l15;
        offA[m] = row * 64 + ((quad ^ ((row >> 1) & 3)) << 4);
    }
#pragma unroll
    for (int j = 0; j < 4; ++j) {
        int row = waveN + j * 16 + l15;
        offW[j] = row * 64 + ((quad ^ ((row >> 1) & 3)) << 4);
    }

    // Staging constants: chunk c = it*512 + tid; row = c>>2 (it=1 -> +128, same swizzle),
    // colByte = ((c&3) ^ ((row>>1)&3))<<4. LDS dest linear: c*16 (wave-uniform base + lane*16).
    const int    ldsOff = tid * 16;
    const size_t gOff   = (size_t)(tid >> 2) * (size_t)(K_TOT * 2)
                        + (size_t)(((tid & 3) ^ ((tid >> 3) & 3)) << 4);

    const char* Ab = (const char*)A + (size_t)mBlk * (size_t)(K_TOT * 2);
    const char* Wb = (const char*)W + (size_t)nBlk * (size_t)(K_TOT * 2);
    char* const sAc = (char*)&sA[0][0][0][0];
    char* const sWc = (char*)&sW[0][0][0][0];

#define STAGE(gbase, kElem, ldsregion) do {                                   \
        const char* _g = (gbase) + (size_t)(kElem) * 2 + gOff;                \
        char*       _l = (ldsregion) + ldsOff;                                \
        gload_lds16(_g, _l);                                                  \
        gload_lds16(_g + (size_t)128 * (K_TOT * 2), _l + 8192);               \
    } while (0)

    floatx4 acc[8][4];
#pragma unroll
    for (int m = 0; m < 8; ++m)
#pragma unroll
        for (int j = 0; j < 4; ++j)
            acc[m][j] = (floatx4){0.f, 0.f, 0.f, 0.f};

    // Prologue: tile0 (4 halves) + tile1 (3 halves); vmcnt(6) -> tile0 landed.
    STAGE(Ab, 0,      REG4(sAc, 0, 0));
    STAGE(Wb, 0,      REG4(sWc, 0, 0));
    STAGE(Ab, 32,     REG4(sAc, 0, 1));
    STAGE(Wb, 32,     REG4(sWc, 0, 1));
    STAGE(Ab, BK,     REG4(sAc, 1, 0));
    STAGE(Wb, BK,     REG4(sWc, 1, 0));
    STAGE(Ab, BK + 32, REG4(sAc, 1, 1));
    VMCNT(6);
    BAR();

    shortx8 af[8], wf0, wf1;

#define MFMA16(J0, J1)                                                        \
    __builtin_amdgcn_s_setprio(1);                                            \
    _Pragma("unroll")                                                         \
    for (int m = 0; m < 8; ++m) {                                             \
        acc[m][J0] = __builtin_amdgcn_mfma_f32_16x16x32_bf16(af[m], wf0, acc[m][J0], 0, 0, 0); \
        acc[m][J1] = __builtin_amdgcn_mfma_f32_16x16x32_bf16(af[m], wf1, acc[m][J1], 0, 0, 0); \
    }                                                                         \
    __builtin_amdgcn_s_setprio(0);

#pragma unroll 2
    for (int t = 0; t < NT; ++t) {
        const int cur = t & 1, nxt = cur ^ 1;
        const char* rA0 = REG4(sAc, cur, 0);
        const char* rA1 = REG4(sAc, cur, 1);
        const char* rW0 = REG4(sWc, cur, 0);
        const char* rW1 = REG4(sWc, cur, 1);

        // ---- P0: ks=0, N lo ----
#pragma unroll
        for (int m = 0; m < 8; ++m) af[m] = *(const shortx8*)(rA0 + offA[m]);
        wf0 = *(const shortx8*)(rW0 + offW[0]);
        wf1 = *(const shortx8*)(rW0 + offW[1]);
        if (t + 1 < NT) STAGE(Wb, (t + 1) * BK + 32, REG4(sWc, nxt, 1));
        BAR();
        MFMA16(0, 1);
        BAR();

        // ---- P1: ks=0, N hi ----
        wf0 = *(const shortx8*)(rW0 + offW[2]);
        wf1 = *(const shortx8*)(rW0 + offW[3]);
        if (t + 2 < NT) STAGE(Ab, (t + 2) * BK, REG4(sAc, cur, 0));
        BAR();
        MFMA16(2, 3);
        BAR();

        // ---- P2: ks=1, N lo ----
#pragma unroll
        for (int m = 0; m < 8; ++m) af[m] = *(const shortx8*)(rA1 + offA[m]);
        wf0 = *(const shortx8*)(rW1 + offW[0]);
        wf1 = *(const shortx8*)(rW1 + offW[1]);
        if (t + 2 < NT) STAGE(Wb, (t + 2) * BK, REG4(sWc, cur, 0));
        BAR();
        MFMA16(0, 1);
        BAR();

        // ---- P3: ks=1, N hi ----
        wf0 = *(const shortx8*)(rW1 + offW[2]);
        wf1 = *(const shortx8*)(rW1 + offW[3]);
        if (t + 2 < NT) STAGE(Ab, (t + 2) * BK + 32, REG4(sAc, cur, 1));
        BAR();
        MFMA16(2, 3);
        if (t < NT - 2) { VMCNT(6); } else { VMCNT(0); }
        BAR();
    }

    // Epilogue: C/D layout col = lane&15, row = quad*4 + reg (measured m89/m91)
#pragma unroll
    for (int j = 0; j < 4; ++j) {
        int col = nBlk + waveN + j * 16 + l15;
        float sc = scale[col];
        float bi = bias[col];
#pragma unroll
        for (int m = 0; m < 8; ++m) {
            int row0 = mBlk + waveM + m * 16 + quad * 4;
#pragma unroll
            for (int r = 0; r < 4; ++r)
                out[(size_t)(row0 + r) * N_TOT + col] = acc[m][j][r] * sc + bi;
        }
    }
}

// ---------------- launch ----------------

extern "C" void kernel_launch(void* const* d_in, const int* in_sizes, int n_in,
                              void* d_out, int out_size, void* d_ws, size_t ws_size,
                              hipStream_t stream) {
    const float* inp    = (const float*)d_in[0];   // [B,S,K] fp32
    const int*   weight = (const int*)d_in[1];     // [N,K] int32 (int8-valued)
    const float* wscale = (const float*)d_in[2];   // [N]
    const float* bias   = (const float*)d_in[3];   // [N]
    float* out = (float*)d_out;

    // Workspace: A_bf16 (64 MB) then W_bf16 (128 MB)
    unsigned short* Abf = (unsigned short*)d_ws;
    unsigned short* Wbf = Abf + (size_t)M_TOT * K_TOT;

    {
        size_t n4 = (size_t)M_TOT * K_TOT / 4;  // 8,388,608
        cvt_a_kernel<<<(unsigned)(n4 / 256), 256, 0, stream>>>(inp, Abf);
    }
    {
        size_t n4 = (size_t)N_TOT * K_TOT / 4;  // 16,777,216
        cvt_w_kernel<<<(unsigned)(n4 / 256), 256, 0, stream>>>(weight, Wbf);
    }

    dim3 grid((N_TOT / BN) * (M_TOT / BM));  // 2048 blocks, 1D (XCD swizzle in-kernel)
    gemm_bf16_kernel<<<grid, 512, 0, stream>>>(Abf, Wbf, wscale, bias, out);
}